// Round 6
// baseline (145.901 us; speedup 1.0000x reference)
//
#include <hip/hip_runtime.h>
#include <hip/hip_bf16.h>

typedef __bf16 bf16_t;
typedef bf16_t bf16x4 __attribute__((ext_vector_type(4)));
typedef bf16_t bf16x8 __attribute__((ext_vector_type(8)));
typedef float  f32x4  __attribute__((ext_vector_type(4)));

#define IN_F   1024
#define OUT_F  1024
#define RANK   8
#define NE     8
#define BATCH  32
#define SEQ    1024
#define M_TOT  (BATCH * SEQ)
#define SCALE  0.125f

#define GLOAD_LDS16(g, l)                                                     \
  __builtin_amdgcn_global_load_lds(                                           \
      (const __attribute__((address_space(1))) void*)(g),                     \
      (__attribute__((address_space(3))) void*)(l), 16, 0, 0)

#define CFENCE asm volatile("" ::: "memory")
#define BAR()                                                                 \
  do { CFENCE; __builtin_amdgcn_s_barrier(); CFENCE; } while (0)
#define VMCNT(n) asm volatile("s_waitcnt vmcnt(" #n ")" ::: "memory")

// ---------------------------------------------------------------------------
// Kernel 1: W_eff[e][o][d] = bf16( W[o][d] + SCALE * sum_r Bw[e][o][r]*A[e][r][d] )
// ---------------------------------------------------------------------------
__global__ __launch_bounds__(256) void build_weff(
    const float* __restrict__ W, const float* __restrict__ A,
    const float* __restrict__ Bw, bf16_t* __restrict__ weff) {
  const int e  = blockIdx.x >> 10;
  const int o  = blockIdx.x & 1023;
  const int d0 = threadIdx.x << 2;

  f32x4 acc = *(const f32x4*)(W + ((size_t)o << 10) + d0);
  const float* bwr = Bw + (((size_t)e << 10) + o) * RANK;
  const float* ab  = A + (((size_t)e * RANK) << 10) + d0;
#pragma unroll
  for (int r = 0; r < RANK; ++r) {
    const float s = SCALE * bwr[r];
    const f32x4 a4 = *(const f32x4*)(ab + ((size_t)r << 10));
    acc += s * a4;
  }
  bf16x4 ov;
#pragma unroll
  for (int j = 0; j < 4; ++j) ov[j] = (bf16_t)acc[j];
  *(bf16x4*)(weff + (((size_t)e << 10) + o) * IN_F + d0) = ov;
}

// ---------------------------------------------------------------------------
// Kernel 2: x fp32 -> bf16
// ---------------------------------------------------------------------------
__global__ __launch_bounds__(256) void cvt_x(const float* __restrict__ x,
                                             bf16_t* __restrict__ xb, int n4) {
  int i = blockIdx.x * 256 + threadIdx.x;
  const int stride = gridDim.x * 256;
  for (; i < n4; i += stride) {
    const f32x4 v = *(const f32x4*)(x + ((size_t)i << 2));
    bf16x4 o;
#pragma unroll
    for (int j = 0; j < 4; ++j) o[j] = (bf16_t)v[j];
    *(bf16x4*)(xb + ((size_t)i << 2)) = o;
  }
}

// ---------------------------------------------------------------------------
// Kernel 3: 256x256 tile, BK=32 phases (32 of them), 8 waves (2M x 4N).
// CROSS-BARRIER B-FRAGMENT PREFETCH: phase p's B-frags were ds_read during
// phase p-1 (into the alternate named set), so MFMAs start right after the
// barrier gated only on af[0]. LDS: A 2-region, B 4-region cycling (96 KiB).
// Per phase: VMCNT(0) [4 loads in flight, ~1-phase cover]; BAR;
//   ASTAGE(p+1)->A[(p+1)&1]; BSTAGE(p+2)->B[(p+2)&3];   (4 gload_lds)
//   af reads (8) from A[p&1]; bfr_next reads (4) from B[(p+1)&3];
//   32 MFMA consuming af + bfr_prev.
// WAR: every staged region's last reader is >=1 barrier behind (A: read in
// p-1, written in p; B: read in p-3, written in p). All indices static
// (loop unrolled x4 phases).
// ---------------------------------------------------------------------------
__global__ __launch_bounds__(512, 2) void gemm256(
    const bf16_t* __restrict__ xb, const bf16_t* __restrict__ weff,
    const float* __restrict__ bias, const int* __restrict__ sid,
    float* __restrict__ out) {
  __shared__ bf16_t lds_a[2][8192];  // 32 KiB, region = p&1
  __shared__ bf16_t lds_b[4][8192];  // 64 KiB, region = p&3

  const int bid0 = blockIdx.x;
  const int wgid = ((bid0 & 7) << 6) + (bid0 >> 3);  // XCD chunked (512 wgs)
  const int mb = wgid >> 2, nb = wgid & 3;
  const int m0 = mb << 8, n0 = nb << 8;
  const int e = sid[mb >> 2];

  const int tid = threadIdx.x;
  const int lane = tid & 63, wid = tid >> 6;
  const int wm = wid >> 2, wn = wid & 3;

  const bf16_t* agbase = xb + ((size_t)m0 << 10);
  const bf16_t* bgbase = weff + ((size_t)e << 20) + ((size_t)n0 << 10);

  // staging offsets (R2-proven): instr i covers LDS row r = wid*32+i*16+
  // (lane>>2), granule lane&3 linear; source granule pre-swizzled.
  int soff[2];
#pragma unroll
  for (int i = 0; i < 2; ++i) {
    const int r = (wid << 5) + (i << 4) + (lane >> 2);
    const int sg = (lane & 3) ^ ((r >> 1) & 3);
    soff[i] = (r << 10) + (sg << 3);
  }

  // fragment read offsets (R2-proven swizzle), within one [256][32] region
  int aoff[8], boff[4];
#pragma unroll
  for (int mi = 0; mi < 8; ++mi) {
    const int r = (wm << 7) + (mi << 4) + (lane & 15);
    const int g = (lane >> 4) ^ ((r >> 1) & 3);
    aoff[mi] = (r << 5) + (g << 3);
  }
#pragma unroll
  for (int ni = 0; ni < 4; ++ni) {
    const int r = (wn << 6) + (ni << 4) + (lane & 15);
    const int g = (lane >> 4) ^ ((r >> 1) & 3);
    boff[ni] = (r << 5) + (g << 3);
  }

  f32x4 acc[8][4] = {};
  bf16x8 af[8], bfrE[4], bfrO[4];

#define ASTAGE(kp, ra)                                                        \
  do {                                                                        \
    bf16_t* _d = &lds_a[ra][wid << 10];                                       \
    const int _kc = (kp) << 5;                                                \
    GLOAD_LDS16(agbase + _kc + soff[0], _d);                                  \
    GLOAD_LDS16(agbase + _kc + soff[1], _d + 512);                            \
  } while (0)

#define BSTAGE(kp, rb)                                                        \
  do {                                                                        \
    bf16_t* _d = &lds_b[rb][wid << 10];                                       \
    const int _kc = (kp) << 5;                                                \
    GLOAD_LDS16(bgbase + _kc + soff[0], _d);                                  \
    GLOAD_LDS16(bgbase + _kc + soff[1], _d + 512);                            \
  } while (0)

#define READ_AF(ra)                                                           \
  do {                                                                        \
    const bf16_t* _ab = &lds_a[ra][0];                                        \
    _Pragma("unroll") for (int mi = 0; mi < 8; ++mi)                          \
        af[mi] = *(const bf16x8*)(_ab + aoff[mi]);                            \
  } while (0)

#define READ_BFR(SET, rb)                                                     \
  do {                                                                        \
    const bf16_t* _bb = &lds_b[rb][0];                                        \
    _Pragma("unroll") for (int ni = 0; ni < 4; ++ni)                          \
        SET[ni] = *(const bf16x8*)(_bb + boff[ni]);                           \
  } while (0)

#define MFMAS(SET)                                                            \
  do {                                                                        \
    __builtin_amdgcn_s_setprio(1);                                            \
    _Pragma("unroll") for (int mi = 0; mi < 8; ++mi)                          \
        _Pragma("unroll") for (int ni = 0; ni < 4; ++ni)                      \
            acc[mi][ni] = __builtin_amdgcn_mfma_f32_16x16x32_bf16(            \
                af[mi], SET[ni], acc[mi][ni], 0, 0, 0);                       \
    __builtin_amdgcn_s_setprio(0);                                            \
  } while (0)

  // -------- prologue: A(0)->A0, B(0)->B0, B(1)->B1; prefetch bfrE(0) -------
  ASTAGE(0, 0);
  BSTAGE(0, 0);
  BSTAGE(1, 1);
  VMCNT(0);
  BAR();
  READ_BFR(bfrE, 0);

  // -------- main loop: 7 x 4 phases = p 0..27 --------
  for (int jj = 0; jj < 7; ++jj) {
    const int p = jj << 2;
    // phase p+0: A reg0, consume bfrE, prefetch bfrO from B[1]
    VMCNT(0); BAR();
    ASTAGE(p + 1, 1); BSTAGE(p + 2, 2);
    READ_AF(0);  READ_BFR(bfrO, 1);
    MFMAS(bfrE);
    // phase p+1: A reg1, consume bfrO, prefetch bfrE from B[2]
    VMCNT(0); BAR();
    ASTAGE(p + 2, 0); BSTAGE(p + 3, 3);
    READ_AF(1);  READ_BFR(bfrE, 2);
    MFMAS(bfrO);
    // phase p+2: A reg0, consume bfrE, prefetch bfrO from B[3]
    VMCNT(0); BAR();
    ASTAGE(p + 3, 1); BSTAGE(p + 4, 0);
    READ_AF(0);  READ_BFR(bfrO, 3);
    MFMAS(bfrE);
    // phase p+3: A reg1, consume bfrO, prefetch bfrE from B[0]
    VMCNT(0); BAR();
    ASTAGE(p + 4, 0); BSTAGE(p + 5, 1);
    READ_AF(1);  READ_BFR(bfrE, 0);
    MFMAS(bfrO);
  }

  // -------- tail: phases 28..31 --------
  // phase 28
  VMCNT(0); BAR();
  ASTAGE(29, 1); BSTAGE(30, 2);
  READ_AF(0);  READ_BFR(bfrO, 1);
  MFMAS(bfrE);
  // phase 29
  VMCNT(0); BAR();
  ASTAGE(30, 0); BSTAGE(31, 3);
  READ_AF(1);  READ_BFR(bfrE, 2);
  MFMAS(bfrO);
  // phase 30
  VMCNT(0); BAR();
  ASTAGE(31, 1);
  READ_AF(0);  READ_BFR(bfrO, 3);
  MFMAS(bfrE);
  // phase 31
  VMCNT(0); BAR();
  READ_AF(1);
  MFMAS(bfrO);

  // epilogue: C/D layout col=lane&15, row=(lane>>4)*4+j; nontemporal stores
  const int R0 = m0 + (wm << 7);
  const int C0 = n0 + (wn << 6);
  const int crow = (lane >> 4) << 2;
  const int ccol = lane & 15;
#pragma unroll
  for (int ni = 0; ni < 4; ++ni) {
    const int col = C0 + (ni << 4) + ccol;
    const float bv = bias[col];
#pragma unroll
    for (int mi = 0; mi < 8; ++mi) {
      const int row = R0 + (mi << 4) + crow;
#pragma unroll
      for (int j2 = 0; j2 < 4; ++j2)
        __builtin_nontemporal_store(acc[mi][ni][j2] + bv,
                                    &out[((size_t)(row + j2) << 10) + col]);
    }
  }
#undef ASTAGE
#undef BSTAGE
#undef READ_AF
#undef READ_BFR
#undef MFMAS
}

// ---------------------------------------------------------------------------
// Fallback (ws too small): naive fp32.
// ---------------------------------------------------------------------------
__global__ __launch_bounds__(256) void lora_naive(
    const float* __restrict__ x, const float* __restrict__ W,
    const float* __restrict__ bias, const float* __restrict__ A,
    const float* __restrict__ Bw, const int* __restrict__ sid,
    float* __restrict__ out) {
  const int m = blockIdx.x;
  const int e = sid[m >> 10];
  __shared__ float xs[IN_F];
  __shared__ float h[RANK];
  const int tid = threadIdx.x;
  for (int i = tid; i < IN_F; i += 256) xs[i] = x[((size_t)m << 10) + i];
  __syncthreads();
  if (tid < RANK) {
    float s = 0.f;
    const float* ar = A + (((size_t)e * RANK + tid) << 10);
    for (int d = 0; d < IN_F; ++d) s += xs[d] * ar[d];
    h[tid] = s * SCALE;
  }
  __syncthreads();
  for (int o = tid; o < OUT_F; o += 256) {
    const float* wr = W + ((size_t)o << 10);
    float s = 0.f;
    for (int d = 0; d < IN_F; ++d) s += xs[d] * wr[d];
    const float* bwr = Bw + (((size_t)e << 10) + o) * RANK;
    float l = 0.f;
#pragma unroll
    for (int r = 0; r < RANK; ++r) l += h[r] * bwr[r];
    out[((size_t)m << 10) + o] = s + bias[o] + l;
  }
}

extern "C" void kernel_launch(void* const* d_in, const int* in_sizes, int n_in,
                              void* d_out, int out_size, void* d_ws,
                              size_t ws_size, hipStream_t stream) {
  const float* x   = (const float*)d_in[0];
  const float* W   = (const float*)d_in[1];
  const float* b   = (const float*)d_in[2];
  const float* A   = (const float*)d_in[3];
  const float* Bw  = (const float*)d_in[4];
  const int*   sid = (const int*)d_in[5];
  float* out = (float*)d_out;

  const size_t weff_bytes = (size_t)NE * OUT_F * IN_F * 2;  // 16 MiB
  const size_t xb_bytes   = (size_t)M_TOT * IN_F * 2;       // 64 MiB

  if (ws_size >= weff_bytes + xb_bytes) {
    bf16_t* weff = (bf16_t*)d_ws;
    bf16_t* xb   = (bf16_t*)((char*)d_ws + weff_bytes);
    hipLaunchKernelGGL(build_weff, dim3(NE * OUT_F), dim3(256), 0, stream,
                       W, A, Bw, weff);
    hipLaunchKernelGGL(cvt_x, dim3(4096), dim3(256), 0, stream,
                       x, xb, M_TOT * IN_F / 4);
    hipLaunchKernelGGL(gemm256, dim3((M_TOT / 256) * (OUT_F / 256)),
                       dim3(512), 0, stream, xb, weff, b, sid, out);
  } else {
    hipLaunchKernelGGL(lora_naive, dim3(M_TOT), dim3(256), 0, stream,
                       x, W, b, A, Bw, sid, out);
  }
}

// Round 7
// 141.098 us; speedup vs baseline: 1.0340x; 1.0340x over previous
//
#include <hip/hip_runtime.h>
#include <hip/hip_bf16.h>

typedef __bf16 bf16_t;
typedef bf16_t bf16x4 __attribute__((ext_vector_type(4)));
typedef bf16_t bf16x8 __attribute__((ext_vector_type(8)));
typedef float  f32x4  __attribute__((ext_vector_type(4)));

#define IN_F   1024
#define OUT_F  1024
#define RANK   8
#define NE     8
#define BATCH  32
#define SEQ    1024
#define M_TOT  (BATCH * SEQ)
#define SCALE  0.125f
#define NT     16   // K / 64

#define GLOAD_LDS16(g, l)                                                     \
  __builtin_amdgcn_global_load_lds(                                           \
      (const __attribute__((address_space(1))) void*)(g),                     \
      (__attribute__((address_space(3))) void*)(l), 16, 0, 0)

#define CFENCE asm volatile("" ::: "memory")
#define BAR()                                                                 \
  do { CFENCE; __builtin_amdgcn_s_barrier(); CFENCE; } while (0)
#define VMCNT(n) asm volatile("s_waitcnt vmcnt(" #n ")" ::: "memory")

// ---------------------------------------------------------------------------
// Kernel 1 (merged prep): blocks [0, 8192) build W_eff; blocks [8192, 10240)
// convert x fp32 -> bf16 (grid-stride).
// ---------------------------------------------------------------------------
__global__ __launch_bounds__(256) void prep(
    const float* __restrict__ W, const float* __restrict__ A,
    const float* __restrict__ Bw, const float* __restrict__ x,
    bf16_t* __restrict__ weff, bf16_t* __restrict__ xb) {
  const int bid = blockIdx.x;
  if (bid < NE * OUT_F) {
    const int e  = bid >> 10;
    const int o  = bid & 1023;
    const int d0 = threadIdx.x << 2;
    f32x4 acc = *(const f32x4*)(W + ((size_t)o << 10) + d0);
    const float* bwr = Bw + (((size_t)e << 10) + o) * RANK;
    const float* ab  = A + (((size_t)e * RANK) << 10) + d0;
#pragma unroll
    for (int r = 0; r < RANK; ++r) {
      const float s = SCALE * bwr[r];
      const f32x4 a4 = *(const f32x4*)(ab + ((size_t)r << 10));
      acc += s * a4;
    }
    bf16x4 ov;
#pragma unroll
    for (int j = 0; j < 4; ++j) ov[j] = (bf16_t)acc[j];
    *(bf16x4*)(weff + (((size_t)e << 10) + o) * IN_F + d0) = ov;
  } else {
    const int cb = bid - NE * OUT_F;
    int i = cb * 256 + threadIdx.x;
    const int stride = 2048 * 256;
    const int n4 = M_TOT * IN_F / 4;
    for (; i < n4; i += stride) {
      const f32x4 v = *(const f32x4*)(x + ((size_t)i << 2));
      bf16x4 o;
#pragma unroll
      for (int j = 0; j < 4; ++j) o[j] = (bf16_t)v[j];
      *(bf16x4*)(xb + ((size_t)i << 2)) = o;
    }
  }
}

// ---------------------------------------------------------------------------
// Kernel 2: 256x256 tile, BK=64, 8 waves (2M x 4N). m201-faithful fine-phase
// schedule: 4 phases per K-tile, each {4-8 ds_read_b128; stage 1 half-tile
// (2 gload_lds); [vmcnt(6) at P4]; BAR; 16 MFMA (setprio); BAR}.
// Stage plan for tile j (buf c=j&1):
//   P1: A(j+1)h1 -> buf 1-c   (region last read P4(j-1), >=1 bar behind)
//   P2: B(j+2)h0 -> buf c     (last read P1(j))
//   P3: A(j+2)h0 -> buf c     (last read P2(j))
//   P4: B(j+2)h1 -> buf c     (last read P3(j)) + VMCNT(6)
// vmcnt(6)=3 half-tiles kept: retires everything of tiles <= j+1 exactly;
// never drains in steady state (T4). Tail: vmcnt(0) at P4(14) only.
// ---------------------------------------------------------------------------
__global__ __launch_bounds__(512, 2) void gemm256(
    const bf16_t* __restrict__ xb, const bf16_t* __restrict__ weff,
    const float* __restrict__ bias, const int* __restrict__ sid,
    float* __restrict__ out) {
  __shared__ bf16_t lds_a[2][2][8192];  // [buf][kh][256 rows x 32 k] 64 KiB
  __shared__ bf16_t lds_b[2][2][8192];  // 64 KiB

  const int bid0 = blockIdx.x;
  const int wgid = ((bid0 & 7) << 6) + (bid0 >> 3);  // XCD chunked (512 wgs)
  const int mb = wgid >> 2, nb = wgid & 3;
  const int m0 = mb << 8, n0 = nb << 8;
  const int e = sid[mb >> 2];

  const int tid = threadIdx.x;
  const int lane = tid & 63, wid = tid >> 6;
  const int wm = wid >> 2, wn = wid & 3;

  const bf16_t* agbase = xb + ((size_t)m0 << 10);
  const bf16_t* bgbase = weff + ((size_t)e << 20) + ((size_t)n0 << 10);

  // staging offsets (R2-proven): instr i covers LDS row r = wid*32+i*16+
  // (lane>>2), granule lane&3 linear; source granule pre-swizzled.
  int soff[2];
#pragma unroll
  for (int i = 0; i < 2; ++i) {
    const int r = (wid << 5) + (i << 4) + (lane >> 2);
    const int sg = (lane & 3) ^ ((r >> 1) & 3);
    soff[i] = (r << 10) + (sg << 3);
  }

  // fragment read offsets (R2-proven swizzle), within one [256][32] region
  int aoff[8], boff[4];
#pragma unroll
  for (int mi = 0; mi < 8; ++mi) {
    const int r = (wm << 7) + (mi << 4) + (lane & 15);
    const int g = (lane >> 4) ^ ((r >> 1) & 3);
    aoff[mi] = (r << 5) + (g << 3);
  }
#pragma unroll
  for (int ni = 0; ni < 4; ++ni) {
    const int r = (wn << 6) + (ni << 4) + (lane & 15);
    const int g = (lane >> 4) ^ ((r >> 1) & 3);
    boff[ni] = (r << 5) + (g << 3);
  }

  f32x4 acc[8][4] = {};
  bf16x8 afq[4], bf0[4], bf1[4];

#define ASTG(kt, c, kh)                                                       \
  do {                                                                        \
    bf16_t* _d = &lds_a[c][kh][wid << 10];                                    \
    const int _kc = ((kt) << 6) + ((kh) << 5);                                \
    GLOAD_LDS16(agbase + _kc + soff[0], _d);                                  \
    GLOAD_LDS16(agbase + _kc + soff[1], _d + 512);                            \
  } while (0)

#define BSTG(kt, c, kh)                                                       \
  do {                                                                        \
    bf16_t* _d = &lds_b[c][kh][wid << 10];                                    \
    const int _kc = ((kt) << 6) + ((kh) << 5);                                \
    GLOAD_LDS16(bgbase + _kc + soff[0], _d);                                  \
    GLOAD_LDS16(bgbase + _kc + soff[1], _d + 512);                            \
  } while (0)

#define RDB(SET, c, kh)                                                       \
  do {                                                                        \
    const bf16_t* _bb = &lds_b[c][kh][0];                                     \
    _Pragma("unroll") for (int ni = 0; ni < 4; ++ni)                          \
        SET[ni] = *(const bf16x8*)(_bb + boff[ni]);                           \
  } while (0)

#define RDA(c, kh, mb_)                                                       \
  do {                                                                        \
    const bf16_t* _ab = &lds_a[c][kh][0];                                     \
    _Pragma("unroll") for (int q = 0; q < 4; ++q)                             \
        afq[q] = *(const bf16x8*)(_ab + aoff[(mb_) + q]);                     \
  } while (0)

#define MM(SET, mb_)                                                          \
  do {                                                                        \
    __builtin_amdgcn_s_setprio(1);                                            \
    _Pragma("unroll") for (int q = 0; q < 4; ++q)                             \
        _Pragma("unroll") for (int ni = 0; ni < 4; ++ni)                      \
            acc[(mb_) + q][ni] = __builtin_amdgcn_mfma_f32_16x16x32_bf16(     \
                afq[q], SET[ni], acc[(mb_) + q][ni], 0, 0, 0);                \
    __builtin_amdgcn_s_setprio(0);                                            \
  } while (0)

#define TILE(JV, C, DO_S1, DO_S234, WTAIL)                                    \
  do {                                                                        \
    /* P1 */                                                                  \
    RDB(bf0, C, 0); RDA(C, 0, 0);                                             \
    if (DO_S1) ASTG((JV) + 1, 1 - (C), 1);                                    \
    BAR(); MM(bf0, 0); BAR();                                                 \
    /* P2 */                                                                  \
    RDA(C, 0, 4);                                                             \
    if (DO_S234) BSTG((JV) + 2, C, 0);                                        \
    BAR(); MM(bf0, 4); BAR();                                                 \
    /* P3 */                                                                  \
    RDB(bf1, C, 1); RDA(C, 1, 0);                                             \
    if (DO_S234) ASTG((JV) + 2, C, 0);                                        \
    BAR(); MM(bf1, 0); BAR();                                                 \
    /* P4 */                                                                  \
    RDA(C, 1, 4);                                                             \
    if (DO_S234) BSTG((JV) + 2, C, 1);                                        \
    WTAIL;                                                                    \
    BAR(); MM(bf1, 4); BAR();                                                 \
  } while (0)

  // prologue: T0 resident; queue = [B1h0, A1h0, B1h1] (3 half-tiles)
  ASTG(0, 0, 0); ASTG(0, 0, 1); BSTG(0, 0, 0); BSTG(0, 0, 1);
  BSTG(1, 1, 0); ASTG(1, 1, 0); BSTG(1, 1, 1);
  VMCNT(6);   // retire T0 (8 instr), keep the 3 newest half-tiles
  BAR();

  for (int jj = 0; jj < 7; ++jj) {
    const int j0 = jj << 1;
    TILE(j0, 0, 1, 1, VMCNT(6));
    TILE(j0 + 1, 1, 1, 1, VMCNT(6));
  }
  TILE(14, 0, 1, 0, VMCNT(0));
  TILE(15, 1, 0, 0, (void)0);

  // epilogue: C/D layout col=lane&15, row=(lane>>4)*4+j (plain stores;
  // nontemporal 4B stores caused partial-line write amplification in R5/R6)
  const int R0 = m0 + (wm << 7);
  const int C0 = n0 + (wn << 6);
  const int crow = (lane >> 4) << 2;
  const int ccol = lane & 15;
#pragma unroll
  for (int ni = 0; ni < 4; ++ni) {
    const int col = C0 + (ni << 4) + ccol;
    const float bv = bias[col];
#pragma unroll
    for (int mi = 0; mi < 8; ++mi) {
      const int row = R0 + (mi << 4) + crow;
#pragma unroll
      for (int j2 = 0; j2 < 4; ++j2)
        out[((size_t)(row + j2) << 10) + col] = acc[mi][ni][j2] + bv;
    }
  }
#undef ASTG
#undef BSTG
#undef RDB
#undef RDA
#undef MM
#undef TILE
}

// ---------------------------------------------------------------------------
// Fallback (ws too small): naive fp32.
// ---------------------------------------------------------------------------
__global__ __launch_bounds__(256) void lora_naive(
    const float* __restrict__ x, const float* __restrict__ W,
    const float* __restrict__ bias, const float* __restrict__ A,
    const float* __restrict__ Bw, const int* __restrict__ sid,
    float* __restrict__ out) {
  const int m = blockIdx.x;
  const int e = sid[m >> 10];
  __shared__ float xs[IN_F];
  __shared__ float h[RANK];
  const int tid = threadIdx.x;
  for (int i = tid; i < IN_F; i += 256) xs[i] = x[((size_t)m << 10) + i];
  __syncthreads();
  if (tid < RANK) {
    float s = 0.f;
    const float* ar = A + (((size_t)e * RANK + tid) << 10);
    for (int d = 0; d < IN_F; ++d) s += xs[d] * ar[d];
    h[tid] = s * SCALE;
  }
  __syncthreads();
  for (int o = tid; o < OUT_F; o += 256) {
    const float* wr = W + ((size_t)o << 10);
    float s = 0.f;
    for (int d = 0; d < IN_F; ++d) s += xs[d] * wr[d];
    const float* bwr = Bw + (((size_t)e << 10) + o) * RANK;
    float l = 0.f;
#pragma unroll
    for (int r = 0; r < RANK; ++r) l += h[r] * bwr[r];
    out[((size_t)m << 10) + o] = s + bias[o] + l;
  }
}

extern "C" void kernel_launch(void* const* d_in, const int* in_sizes, int n_in,
                              void* d_out, int out_size, void* d_ws,
                              size_t ws_size, hipStream_t stream) {
  const float* x   = (const float*)d_in[0];
  const float* W   = (const float*)d_in[1];
  const float* b   = (const float*)d_in[2];
  const float* A   = (const float*)d_in[3];
  const float* Bw  = (const float*)d_in[4];
  const int*   sid = (const int*)d_in[5];
  float* out = (float*)d_out;

  const size_t weff_bytes = (size_t)NE * OUT_F * IN_F * 2;  // 16 MiB
  const size_t xb_bytes   = (size_t)M_TOT * IN_F * 2;       // 64 MiB

  if (ws_size >= weff_bytes + xb_bytes) {
    bf16_t* weff = (bf16_t*)d_ws;
    bf16_t* xb   = (bf16_t*)((char*)d_ws + weff_bytes);
    hipLaunchKernelGGL(prep, dim3(NE * OUT_F + 2048), dim3(256), 0, stream,
                       W, A, Bw, x, weff, xb);
    hipLaunchKernelGGL(gemm256, dim3((M_TOT / 256) * (OUT_F / 256)),
                       dim3(512), 0, stream, xb, weff, b, sid, out);
  } else {
    hipLaunchKernelGGL(lora_naive, dim3(M_TOT), dim3(256), 0, stream,
                       x, W, b, A, Bw, sid, out);
  }
}

// Round 8
// 139.975 us; speedup vs baseline: 1.0423x; 1.0080x over previous
//
#include <hip/hip_runtime.h>
#include <hip/hip_bf16.h>

typedef __bf16 bf16_t;
typedef bf16_t bf16x4 __attribute__((ext_vector_type(4)));
typedef bf16_t bf16x8 __attribute__((ext_vector_type(8)));
typedef float  f32x4  __attribute__((ext_vector_type(4)));

#define IN_F   1024
#define OUT_F  1024
#define RANK   8
#define NE     8
#define BATCH  32
#define SEQ    1024
#define M_TOT  (BATCH * SEQ)
#define SCALE  0.125f
#define NT     16   // K / 64

#define GLOAD_LDS16(g, l)                                                     \
  __builtin_amdgcn_global_load_lds(                                           \
      (const __attribute__((address_space(1))) void*)(g),                     \
      (__attribute__((address_space(3))) void*)(l), 16, 0, 0)

#define CFENCE asm volatile("" ::: "memory")
#define BAR()                                                                 \
  do { CFENCE; __builtin_amdgcn_s_barrier(); CFENCE; } while (0)
#define VMCNT(n) asm volatile("s_waitcnt vmcnt(" #n ")" ::: "memory")

// ---------------------------------------------------------------------------
// Kernel 1 (merged prep): blocks [0, 8192) build W_eff; blocks [8192, 10240)
// convert x fp32 -> bf16 (grid-stride).
// ---------------------------------------------------------------------------
__global__ __launch_bounds__(256) void prep(
    const float* __restrict__ W, const float* __restrict__ A,
    const float* __restrict__ Bw, const float* __restrict__ x,
    bf16_t* __restrict__ weff, bf16_t* __restrict__ xb) {
  const int bid = blockIdx.x;
  if (bid < NE * OUT_F) {
    const int e  = bid >> 10;
    const int o  = bid & 1023;
    const int d0 = threadIdx.x << 2;
    f32x4 acc = *(const f32x4*)(W + ((size_t)o << 10) + d0);
    const float* bwr = Bw + (((size_t)e << 10) + o) * RANK;
    const float* ab  = A + (((size_t)e * RANK) << 10) + d0;
#pragma unroll
    for (int r = 0; r < RANK; ++r) {
      const float s = SCALE * bwr[r];
      const f32x4 a4 = *(const f32x4*)(ab + ((size_t)r << 10));
      acc += s * a4;
    }
    bf16x4 ov;
#pragma unroll
    for (int j = 0; j < 4; ++j) ov[j] = (bf16_t)acc[j];
    *(bf16x4*)(weff + (((size_t)e << 10) + o) * IN_F + d0) = ov;
  } else {
    const int cb = bid - NE * OUT_F;
    int i = cb * 256 + threadIdx.x;
    const int stride = 2048 * 256;
    const int n4 = M_TOT * IN_F / 4;
    for (; i < n4; i += stride) {
      const f32x4 v = *(const f32x4*)(x + ((size_t)i << 2));
      bf16x4 o;
#pragma unroll
      for (int j = 0; j < 4; ++j) o[j] = (bf16_t)v[j];
      *(bf16x4*)(xb + ((size_t)i << 2)) = o;
    }
  }
}

// ---------------------------------------------------------------------------
// Kernel 2: 128x128 tile, 4 waves (2x2, 64x64/wave), BK=64, LDS 64 KiB ->
// TWO resident blocks per CU (independent barrier domains overlap pipes).
// Per phase (2 phases/K-tile): {8 ds_read_b128 (tile j, kh); stage next
// half-tile A+B (4 gload_lds); VMCNT(4) [retires exactly the half needed
// next phase, per-wave ledger, never drains]; BAR; 16 MFMA (setprio)}.
// WAR: staged region last read 2 phases (2 bars) earlier; slow-wave pending
// reads always target the other buffer. Swizzle: R2-proven granule XOR.
// ---------------------------------------------------------------------------
__global__ __launch_bounds__(256, 2) void gemm128(
    const bf16_t* __restrict__ xb, const bf16_t* __restrict__ weff,
    const float* __restrict__ bias, const int* __restrict__ sid,
    float* __restrict__ out) {
  __shared__ bf16_t lds_a[2][2][4096];  // [buf][kh][128r x 32k] = 32 KiB
  __shared__ bf16_t lds_b[2][2][4096];  // 32 KiB

  const int bid0 = blockIdx.x;
  const int wgid = ((bid0 & 7) << 8) + (bid0 >> 3);  // XCD chunked, 2048 wgs
  const int mb = wgid >> 3, nb = wgid & 7;           // nb inner: A-panel reuse
  const int m0 = mb << 7, n0 = nb << 7;
  const int e = sid[mb >> 3];

  const int tid = threadIdx.x;
  const int lane = tid & 63, wid = tid >> 6;
  const int wm = wid >> 1, wn = wid & 1;

  const bf16_t* agbase = xb + ((size_t)m0 << 10);
  const bf16_t* bgbase = weff + ((size_t)e << 20) + ((size_t)n0 << 10);

  // staging: instr i covers LDS elems [i*2048 + tid*8 .. +8) of a [128][32]
  // region -> row r = i*64 + tid/4, granule tid&3 (linear dest). Source
  // granule pre-swizzled to match read-side XOR.
  int soff[2];
#pragma unroll
  for (int i = 0; i < 2; ++i) {
    const int r = (i << 6) + (tid >> 2);
    const int sg = (tid & 3) ^ ((r >> 1) & 3);
    soff[i] = (r << 10) + (sg << 3);
  }

  // fragment read offsets within one [128][32] region (swizzled)
  int aoff[4], boff[4];
#pragma unroll
  for (int mi = 0; mi < 4; ++mi) {
    const int r = (wm << 6) + (mi << 4) + (lane & 15);
    const int g = (lane >> 4) ^ ((r >> 1) & 3);
    aoff[mi] = (r << 5) + (g << 3);
  }
#pragma unroll
  for (int ni = 0; ni < 4; ++ni) {
    const int r = (wn << 6) + (ni << 4) + (lane & 15);
    const int g = (lane >> 4) ^ ((r >> 1) & 3);
    boff[ni] = (r << 5) + (g << 3);
  }

  f32x4 acc[4][4] = {};
  bf16x8 af[4], bf[4];

#define ASTG(kt, c, kh)                                                       \
  do {                                                                        \
    bf16_t* _d = &lds_a[c][kh][wid << 9];                                     \
    const int _kc = ((kt) << 6) + ((kh) << 5);                                \
    GLOAD_LDS16(agbase + _kc + soff[0], _d);                                  \
    GLOAD_LDS16(agbase + _kc + soff[1], _d + 2048);                           \
  } while (0)

#define BSTG(kt, c, kh)                                                       \
  do {                                                                        \
    bf16_t* _d = &lds_b[c][kh][wid << 9];                                     \
    const int _kc = ((kt) << 6) + ((kh) << 5);                                \
    GLOAD_LDS16(bgbase + _kc + soff[0], _d);                                  \
    GLOAD_LDS16(bgbase + _kc + soff[1], _d + 2048);                           \
  } while (0)

#define RD(c, kh)                                                             \
  do {                                                                        \
    const bf16_t* _ab = &lds_a[c][kh][0];                                     \
    const bf16_t* _bb = &lds_b[c][kh][0];                                     \
    _Pragma("unroll") for (int mi = 0; mi < 4; ++mi)                          \
        af[mi] = *(const bf16x8*)(_ab + aoff[mi]);                            \
    _Pragma("unroll") for (int ni = 0; ni < 4; ++ni)                          \
        bf[ni] = *(const bf16x8*)(_bb + boff[ni]);                            \
  } while (0)

#define MM()                                                                  \
  do {                                                                        \
    __builtin_amdgcn_s_setprio(1);                                            \
    _Pragma("unroll") for (int mi = 0; mi < 4; ++mi)                          \
        _Pragma("unroll") for (int ni = 0; ni < 4; ++ni)                      \
            acc[mi][ni] = __builtin_amdgcn_mfma_f32_16x16x32_bf16(            \
                af[mi], bf[ni], acc[mi][ni], 0, 0, 0);                        \
    __builtin_amdgcn_s_setprio(0);                                            \
  } while (0)

#define TILE(JV, C)                                                           \
  do {                                                                        \
    /* P1: kh0 */                                                             \
    RD(C, 0);                                                                 \
    ASTG((JV) + 1, 1 - (C), 0); BSTG((JV) + 1, 1 - (C), 0);                   \
    VMCNT(4); BAR();                                                          \
    MM();                                                                     \
    /* P2: kh1 */                                                             \
    RD(C, 1);                                                                 \
    ASTG((JV) + 1, 1 - (C), 1); BSTG((JV) + 1, 1 - (C), 1);                   \
    VMCNT(4); BAR();                                                          \
    MM();                                                                     \
  } while (0)

  // prologue: stage tile 0 fully; keep h1 in flight past the first barrier
  ASTG(0, 0, 0); BSTG(0, 0, 0);
  ASTG(0, 0, 1); BSTG(0, 0, 1);
  VMCNT(4);   // retire tile0 h0; keep h1 (retired at P1(0)'s VMCNT(4))
  BAR();

  for (int jj = 0; jj < 7; ++jj) {
    TILE(2 * jj, 0);
    TILE(2 * jj + 1, 1);
  }
  TILE(14, 0);   // stages tile 15 -> buf 1
  // tile 15 (buf 1), no staging
  RD(1, 0);
  VMCNT(0); BAR();
  MM();
  RD(1, 1);
  MM();

  // epilogue: C/D layout col=lane&15, row=(lane>>4)*4+j
  const int R0 = m0 + (wm << 6);
  const int C0 = n0 + (wn << 6);
  const int crow = (lane >> 4) << 2;
  const int ccol = lane & 15;
#pragma unroll
  for (int ni = 0; ni < 4; ++ni) {
    const int col = C0 + (ni << 4) + ccol;
    const float bv = bias[col];
#pragma unroll
    for (int mi = 0; mi < 4; ++mi) {
      const int row = R0 + (mi << 4) + crow;
#pragma unroll
      for (int j2 = 0; j2 < 4; ++j2)
        out[((size_t)(row + j2) << 10) + col] = acc[mi][ni][j2] + bv;
    }
  }
#undef ASTG
#undef BSTG
#undef RD
#undef MM
#undef TILE
}

// ---------------------------------------------------------------------------
// Fallback (ws too small): naive fp32.
// ---------------------------------------------------------------------------
__global__ __launch_bounds__(256) void lora_naive(
    const float* __restrict__ x, const float* __restrict__ W,
    const float* __restrict__ bias, const float* __restrict__ A,
    const float* __restrict__ Bw, const int* __restrict__ sid,
    float* __restrict__ out) {
  const int m = blockIdx.x;
  const int e = sid[m >> 10];
  __shared__ float xs[IN_F];
  __shared__ float h[RANK];
  const int tid = threadIdx.x;
  for (int i = tid; i < IN_F; i += 256) xs[i] = x[((size_t)m << 10) + i];
  __syncthreads();
  if (tid < RANK) {
    float s = 0.f;
    const float* ar = A + (((size_t)e * RANK + tid) << 10);
    for (int d = 0; d < IN_F; ++d) s += xs[d] * ar[d];
    h[tid] = s * SCALE;
  }
  __syncthreads();
  for (int o = tid; o < OUT_F; o += 256) {
    const float* wr = W + ((size_t)o << 10);
    float s = 0.f;
    for (int d = 0; d < IN_F; ++d) s += xs[d] * wr[d];
    const float* bwr = Bw + (((size_t)e << 10) + o) * RANK;
    float l = 0.f;
#pragma unroll
    for (int r = 0; r < RANK; ++r) l += h[r] * bwr[r];
    out[((size_t)m << 10) + o] = s + bias[o] + l;
  }
}

extern "C" void kernel_launch(void* const* d_in, const int* in_sizes, int n_in,
                              void* d_out, int out_size, void* d_ws,
                              size_t ws_size, hipStream_t stream) {
  const float* x   = (const float*)d_in[0];
  const float* W   = (const float*)d_in[1];
  const float* b   = (const float*)d_in[2];
  const float* A   = (const float*)d_in[3];
  const float* Bw  = (const float*)d_in[4];
  const int*   sid = (const int*)d_in[5];
  float* out = (float*)d_out;

  const size_t weff_bytes = (size_t)NE * OUT_F * IN_F * 2;  // 16 MiB
  const size_t xb_bytes   = (size_t)M_TOT * IN_F * 2;       // 64 MiB

  if (ws_size >= weff_bytes + xb_bytes) {
    bf16_t* weff = (bf16_t*)d_ws;
    bf16_t* xb   = (bf16_t*)((char*)d_ws + weff_bytes);
    hipLaunchKernelGGL(prep, dim3(NE * OUT_F + 2048), dim3(256), 0, stream,
                       W, A, Bw, x, weff, xb);
    hipLaunchKernelGGL(gemm128, dim3((M_TOT / 128) * (OUT_F / 128)),
                       dim3(256), 0, stream, xb, weff, b, sid, out);
  } else {
    hipLaunchKernelGGL(lora_naive, dim3(M_TOT), dim3(256), 0, stream,
                       x, W, b, A, Bw, sid, out);
  }
}